// Round 1
// baseline (101.974 us; speedup 1.0000x reference)
//
#include <hip/hip_runtime.h>
#include <cstddef>

#define NB 8
#define NN 1024
#define NF 32
#define NIDX 4

// ---- ws layout (float offsets) ----
#define OFF_ROW   0u          // rowsum  [8192]
#define OFF_COLP  8192u       // colpart [16][8192]
#define OFF_DINV  139264u     // dinv    [8192]
#define OFF_P     147456u     // p = (w1+2w2)ated X  [8192][4][2]
#define OFF_R     212992u     // r = (-2w2)ated X
#define OFF_S     278528u     // s = (w0+w2)ated X
#define OFF_T     344064u     // t = M p  [2 halves][8192][4][2]
#define OFF_W     475136u     // w = M r  [2][8192][4][2]
#define OFF_Y     606208u     // y = M w  [2][8192][4][2]
#define HSTRIDE   65536       // j-half stride in t/w/y

#if __has_builtin(__builtin_amdgcn_sinf)
#define FSIN(x) __builtin_amdgcn_sinf(x)   // sin(2*pi*x), |x|<0.5 here
#define FCOS(x) __builtin_amdgcn_cosf(x)
#else
#define FSIN(x) __sinf((x) * 6.283185307179586f)
#define FCOS(x) __cosf((x) * 6.283185307179586f)
#endif

// Fused row+column sums of As in one read of adj.
// grid (NB, 16), 256 threads. Block = 64 rows of batch b.
__global__ __launch_bounds__(256) void k_sums(const float* __restrict__ adj,
                                              float* __restrict__ rowsum,
                                              float* __restrict__ colpart) {
  int b = blockIdx.x, jc = blockIdx.y;
  int t = threadIdx.x, lane = t & 63, w = t >> 6;
  float colreg[16];
  #pragma unroll
  for (int i = 0; i < 16; ++i) colreg[i] = 0.f;
  int r0 = jc*64 + w*16;
  for (int rr = 0; rr < 16; ++rr) {
    const float4* row4 = reinterpret_cast<const float4*>(adj + ((size_t)b*NN + r0 + rr)*NN);
    float rs = 0.f;
    #pragma unroll
    for (int cq = 0; cq < 4; ++cq) {
      float4 v = row4[cq*64 + lane];
      colreg[cq*4+0] += v.x; colreg[cq*4+1] += v.y;
      colreg[cq*4+2] += v.z; colreg[cq*4+3] += v.w;
      rs += (v.x + v.y) + (v.z + v.w);
    }
    #pragma unroll
    for (int o = 32; o > 0; o >>= 1) rs += __shfl_xor(rs, o);
    if (lane == 0) rowsum[b*NN + r0 + rr] = rs;
  }
  __shared__ float cacc[4][NN];
  #pragma unroll
  for (int cq = 0; cq < 4; ++cq) {
    #pragma unroll
    for (int x = 0; x < 4; ++x) cacc[w][cq*256 + lane*4 + x] = colreg[cq*4+x];
  }
  __syncthreads();
  for (int c = t; c < NN; c += 256)
    colpart[((size_t)jc*NB + b)*NN + c] = cacc[0][c] + cacc[1][c] + cacc[2][c] + cacc[3][c];
}

__global__ void k_dinv(const float* __restrict__ rowsum, const float* __restrict__ colpart,
                       float* __restrict__ dinv) {
  int g = blockIdx.x*256 + threadIdx.x;
  float cs = 0.f;
  #pragma unroll
  for (int k = 0; k < 16; ++k) cs += colpart[k*(NB*NN) + g];
  float D = 0.5f*(rowsum[g] + cs);   // D_i = sum_j 0.5*(a_ij + a_ji)
  dinv[g] = (D > 0.f) ? (1.0f / sqrtf(D)) : 0.f;
}

// Per-node feature contractions: s=(w0+w2).X, p=(w1+2w2).X, r=(-2w2).X  (complex, weights real)
__global__ __launch_bounds__(256) void k_prep(const float* __restrict__ Xr, const float* __restrict__ Xi,
                       const float* __restrict__ weight,
                       float* __restrict__ svec, float* __restrict__ pvec, float* __restrict__ rvec) {
  __shared__ float wsm[NIDX*3*NF];
  int t = threadIdx.x;
  for (int e = t; e < NIDX*3*NF; e += 256) wsm[e] = weight[e];
  __syncthreads();
  int gid = blockIdx.x*256 + t;
  const float* xr = Xr + (size_t)gid*NF;
  const float* xi = Xi + (size_t)gid*NF;
  float acc[NIDX][3][2];
  #pragma unroll
  for (int x = 0; x < NIDX; ++x)
    #pragma unroll
    for (int v = 0; v < 3; ++v) { acc[x][v][0] = 0.f; acc[x][v][1] = 0.f; }
  for (int f = 0; f < NF; ++f) {
    float xrf = xr[f], xif = xi[f];
    #pragma unroll
    for (int x = 0; x < NIDX; ++x) {
      float w0 = wsm[x*96 + f], w1 = wsm[x*96 + 32 + f], w2 = wsm[x*96 + 64 + f];
      float av = w0 + w2, bv = w1 + 2.f*w2, cv = -2.f*w2;
      acc[x][0][0] += av*xrf; acc[x][0][1] += av*xif;
      acc[x][1][0] += bv*xrf; acc[x][1][1] += bv*xif;
      acc[x][2][0] += cv*xrf; acc[x][2][1] += cv*xif;
    }
  }
  #pragma unroll
  for (int x = 0; x < NIDX; ++x) {
    size_t o = (size_t)gid*8 + x*2;
    svec[o] = acc[x][0][0]; svec[o+1] = acc[x][0][1];
    pvec[o] = acc[x][1][0]; pvec[o+1] = acc[x][1][1];
    rvec[o] = acc[x][2][0]; rvec[o+1] = acc[x][2][1];
  }
}

// out[i] += sum_j M_ij * v_j for all 4 freqs at once; M_ij = dinv_i*As_ij*dinv_j * e^{i*2*pi*q*(a_ij-a_ji)}
// NV=2: two input vectors (p,r) -> (t,w).  NV=1 (+SUMH sums the two j-half partials of the input): w -> y.
// grid (NN/32, NB, 2 j-halves), 256 threads. dinv_j is pre-multiplied into vbuf at staging.
template<int NV, bool SUMH>
__global__ __launch_bounds__(256) void k_pass(const float* __restrict__ adj,
                                              const float* __restrict__ dinv,
                                              const float* __restrict__ vinA,
                                              const float* __restrict__ vinB,
                                              float* __restrict__ outA,
                                              float* __restrict__ outB) {
  constexpr int TI = 32, TJ = 64, SL = NV*8;
  __shared__ float Arow[TI][TJ+1];          // pad -> conflict-free
  __shared__ float ATs[TJ][TI+1];
  __shared__ float vbuf[TJ][SL];            // 16B-aligned rows for float4 reads
  __shared__ float red[8*TI*(SL+1)];
  int b = blockIdx.y, i0 = blockIdx.x*TI, jh = blockIdx.z;
  int t = threadIdx.x, ii = t & 31, g = t >> 5;
  float di5 = 0.5f * dinv[b*NN + i0 + ii];
  const float QV[NIDX] = {0.5f, 1.f/3.f, 0.25f, 0.2f};
  float acc[NIDX][NV][2];
  #pragma unroll
  for (int x = 0; x < NIDX; ++x)
    #pragma unroll
    for (int v = 0; v < NV; ++v) { acc[x][v][0] = 0.f; acc[x][v][1] = 0.f; }

  for (int jt = 0; jt < (NN/2)/TJ; ++jt) {
    int j0 = jh*(NN/2) + jt*TJ;
    __syncthreads();
    #pragma unroll
    for (int m = 0; m < 8; ++m) {
      int e = t + 256*m;
      Arow[e>>6][e&63] = adj[((size_t)b*NN + i0 + (e>>6))*NN + j0 + (e&63)];
    }
    #pragma unroll
    for (int m = 0; m < 8; ++m) {
      int e = t + 256*m;
      ATs[e>>5][e&31] = adj[((size_t)b*NN + j0 + (e>>5))*NN + i0 + (e&31)];
    }
    for (int e = t; e < TJ*SL; e += 256) {
      int jj = e / SL, c = e % SL;
      float djv = dinv[b*NN + j0 + jj];
      float val;
      if constexpr (NV == 2) {
        const float* src = (c & 8) ? vinB : vinA;
        val = src[((size_t)b*NN + j0 + jj)*8 + (c & 7)];
      } else {
        size_t o = ((size_t)b*NN + j0 + jj)*8 + c;
        val = vinA[o];
        if constexpr (SUMH) val += vinA[HSTRIDE + o];
      }
      vbuf[jj][c] = djv * val;
    }
    __syncthreads();
    #pragma unroll
    for (int k = 0; k < 8; ++k) {
      int jj = g*8 + k;
      float ar = Arow[ii][jj];
      float ac = ATs[jj][ii];
      float T  = di5 * (ar + ac);      // dinv_i * As_ij  (dinv_j folded into vbuf)
      float dd = ar - ac;              // a_ij - a_ji
      float pv[SL];
      const float4* vb4 = reinterpret_cast<const float4*>(&vbuf[jj][0]);
      #pragma unroll
      for (int q4 = 0; q4 < SL/4; ++q4) {
        float4 f4 = vb4[q4];
        pv[q4*4+0] = f4.x; pv[q4*4+1] = f4.y; pv[q4*4+2] = f4.z; pv[q4*4+3] = f4.w;
      }
      #pragma unroll
      for (int x = 0; x < NIDX; ++x) {
        float u = QV[x] * dd;          // revolutions; |u| < 0.5
        float sn = FSIN(u);
        float cs = FCOS(u);
        float Mr = T * cs, Mi = T * sn;
        #pragma unroll
        for (int v = 0; v < NV; ++v) {
          float vr = pv[v*8 + x*2 + 0];
          float vi = pv[v*8 + x*2 + 1];
          acc[x][v][0] += Mr*vr - Mi*vi;
          acc[x][v][1] += Mr*vi + Mi*vr;
        }
      }
    }
  }
  // reduce the 8 j-groups sharing each row
  #pragma unroll
  for (int x = 0; x < NIDX; ++x)
    #pragma unroll
    for (int v = 0; v < NV; ++v)
      #pragma unroll
      for (int p = 0; p < 2; ++p)
        red[(g*TI + ii)*(SL+1) + v*8 + x*2 + p] = acc[x][v][p];
  __syncthreads();
  for (int e = t; e < TI*SL; e += 256) {
    int row = e / SL, slot = e % SL;
    float s = 0.f;
    #pragma unroll
    for (int gg = 0; gg < 8; ++gg) s += red[(gg*TI + row)*(SL+1) + slot];
    size_t o = (size_t)jh*HSTRIDE + ((size_t)b*NN + i0 + row)*8 + (slot & 7);
    if constexpr (NV == 2) { ((slot & 8) ? outB : outA)[o] = s; }
    else                   { outA[o] = s; }
  }
}

__global__ void k_finish(const float* __restrict__ svec, const float* __restrict__ tvec,
                         const float* __restrict__ yvec, const float* __restrict__ bias,
                         float* __restrict__ out) {
  int w = blockIdx.x*256 + threadIdx.x;  // 0..32767
  int idx = w & 3, gid = w >> 2;
  size_t o = (size_t)gid*8 + idx*2;
  float re = svec[o]   + tvec[o]   + tvec[HSTRIDE + o]     + yvec[o]   + yvec[HSTRIDE + o];
  float im = svec[o+1] + tvec[o+1] + tvec[HSTRIDE + o + 1] + yvec[o+1] + yvec[HSTRIDE + o + 1];
  out[(size_t)gid*4 + idx] = re + bias[idx];
  out[32768 + (size_t)gid*4 + idx] = im;
}

extern "C" void kernel_launch(void* const* d_in, const int* in_sizes, int n_in,
                              void* d_out, int out_size, void* d_ws, size_t ws_size,
                              hipStream_t stream) {
  (void)in_sizes; (void)n_in; (void)out_size; (void)ws_size;
  const float* Xr     = (const float*)d_in[0];
  const float* Xi     = (const float*)d_in[1];
  const float* adj    = (const float*)d_in[2];
  const float* weight = (const float*)d_in[3];
  const float* bias   = (const float*)d_in[4];
  float* ws = (float*)d_ws;
  float* rowsum  = ws + OFF_ROW;
  float* colpart = ws + OFF_COLP;
  float* dinv    = ws + OFF_DINV;
  float* pvec    = ws + OFF_P;
  float* rvec    = ws + OFF_R;
  float* svec    = ws + OFF_S;
  float* tvec    = ws + OFF_T;
  float* wvec    = ws + OFF_W;
  float* yvec    = ws + OFF_Y;
  float* out = (float*)d_out;

  k_sums<<<dim3(NB, 16), 256, 0, stream>>>(adj, rowsum, colpart);
  k_dinv<<<dim3(NB*NN/256), 256, 0, stream>>>(rowsum, colpart, dinv);
  k_prep<<<dim3(NB*NN/256), 256, 0, stream>>>(Xr, Xi, weight, svec, pvec, rvec);
  k_pass<2,false><<<dim3(NN/32, NB, 2), 256, 0, stream>>>(adj, dinv, pvec, rvec, tvec, wvec);
  k_pass<1,true ><<<dim3(NN/32, NB, 2), 256, 0, stream>>>(adj, dinv, wvec, nullptr, yvec, nullptr);
  k_finish<<<dim3(NB*NN*NIDX/256), 256, 0, stream>>>(svec, tvec, yvec, bias, out);
}

// Round 2
// 65.553 us; speedup vs baseline: 1.5556x; 1.5556x over previous
//
#include <hip/hip_runtime.h>
#include <cstddef>

#define NB 8
#define NN 1024
#define NF 32
#define NIDX 4

// ---- ws layout (float offsets) ----
// colpart region is reused for s/p/r after k_dinv consumes it.
#define OFF_ROW   0u
#define OFF_COLP  8192u                 // [64][NB*NN] = 524288
#define OFF_S     8192u                 // aliases colpart (after k_dinv)
#define OFF_P     (8192u + 65536u)
#define OFF_R     (8192u + 131072u)
#define OFF_DINV  532480u               // 8192 + 524288
#define OFF_WT    540672u
#define OFF_WP    606208u               // [JC][65536]; ypart aliases this (safe: wpart dead after k_comb)

#if __has_builtin(__builtin_amdgcn_sinf)
#define FSIN(x) __builtin_amdgcn_sinf(x)   // sin(2*pi*x), |x|<0.5 here
#define FCOS(x) __builtin_amdgcn_cosf(x)
#else
#define FSIN(x) __sinf((x) * 6.283185307179586f)
#define FCOS(x) __cosf((x) * 6.283185307179586f)
#endif

// Fused row+col sums of adj in one read. grid (NB, 64), 512 thr. Strip = 16 rows.
__global__ __launch_bounds__(512) void k_sums(const float* __restrict__ adj,
                                              float* __restrict__ rowsum,
                                              float* __restrict__ colpart) {
  int b = blockIdx.x, strip = blockIdx.y;
  int t = threadIdx.x, lane = t & 63, w = t >> 6;   // 8 waves, 2 rows each
  float colreg[16];
  #pragma unroll
  for (int i = 0; i < 16; ++i) colreg[i] = 0.f;
  int r0 = strip*16 + w*2;
  #pragma unroll
  for (int rr = 0; rr < 2; ++rr) {
    const float4* row4 = reinterpret_cast<const float4*>(adj + ((size_t)b*NN + r0 + rr)*NN);
    float rs = 0.f;
    #pragma unroll
    for (int cq = 0; cq < 4; ++cq) {
      float4 v = row4[cq*64 + lane];
      colreg[cq*4+0] += v.x; colreg[cq*4+1] += v.y;
      colreg[cq*4+2] += v.z; colreg[cq*4+3] += v.w;
      rs += (v.x + v.y) + (v.z + v.w);
    }
    #pragma unroll
    for (int o = 32; o > 0; o >>= 1) rs += __shfl_xor(rs, o);
    if (lane == 0) rowsum[b*NN + r0 + rr] = rs;
  }
  __shared__ float cacc[8][NN];
  #pragma unroll
  for (int cq = 0; cq < 4; ++cq)
    #pragma unroll
    for (int x = 0; x < 4; ++x) cacc[w][cq*256 + lane*4 + x] = colreg[cq*4+x];
  __syncthreads();
  for (int c = t; c < NN; c += 512) {
    float s = 0.f;
    #pragma unroll
    for (int ww = 0; ww < 8; ++ww) s += cacc[ww][c];
    colpart[(size_t)strip*(NB*NN) + b*NN + c] = s;
  }
}

__global__ void k_dinv(const float* __restrict__ rowsum, const float* __restrict__ colpart,
                       float* __restrict__ dinv) {
  int g = blockIdx.x*256 + threadIdx.x;
  float cs = 0.f;
  for (int k = 0; k < 64; ++k) cs += colpart[(size_t)k*(NB*NN) + g];
  float D = 0.5f*(rowsum[g] + cs);
  dinv[g] = (D > 0.f) ? (1.0f / sqrtf(D)) : 0.f;
}

// s=(w0+w2).X, p=(w1+2w2).X, r=dinv*(-2w2).X   (dinv_j pre-folded into pass-1 input)
__global__ __launch_bounds__(256) void k_prep(const float* __restrict__ Xr, const float* __restrict__ Xi,
                       const float* __restrict__ weight, const float* __restrict__ dinv,
                       float* __restrict__ svec, float* __restrict__ pvec, float* __restrict__ rvec) {
  __shared__ float wsm[NIDX*3*NF];
  int t = threadIdx.x;
  for (int e = t; e < NIDX*3*NF; e += 256) wsm[e] = weight[e];
  __syncthreads();
  int gid = blockIdx.x*256 + t;
  const float* xr = Xr + (size_t)gid*NF;
  const float* xi = Xi + (size_t)gid*NF;
  float acc[NIDX][3][2];
  #pragma unroll
  for (int x = 0; x < NIDX; ++x)
    #pragma unroll
    for (int v = 0; v < 3; ++v) { acc[x][v][0] = 0.f; acc[x][v][1] = 0.f; }
  for (int f = 0; f < NF; ++f) {
    float xrf = xr[f], xif = xi[f];
    #pragma unroll
    for (int x = 0; x < NIDX; ++x) {
      float w0 = wsm[x*96 + f], w1 = wsm[x*96 + 32 + f], w2 = wsm[x*96 + 64 + f];
      float av = w0 + w2, bv = w1 + 2.f*w2, cv = -2.f*w2;
      acc[x][0][0] += av*xrf; acc[x][0][1] += av*xif;
      acc[x][1][0] += bv*xrf; acc[x][1][1] += bv*xif;
      acc[x][2][0] += cv*xrf; acc[x][2][1] += cv*xif;
    }
  }
  float dj = dinv[gid];
  #pragma unroll
  for (int x = 0; x < NIDX; ++x) {
    size_t o = (size_t)gid*8 + x*2;
    svec[o] = acc[x][0][0];      svec[o+1] = acc[x][0][1];
    pvec[o] = acc[x][1][0];      pvec[o+1] = acc[x][1][1];
    rvec[o] = dj*acc[x][2][0];   rvec[o+1] = dj*acc[x][2][1];
  }
}

// One M-application: outp[z][b][i][8] = partial_j sum over this block's j-chunk of
//   0.5*dinv_i * (a_ij + a_ji) * e^{i*2pi*q*(a_ij - a_ji)} * vin_j   (vin has dinv_j folded)
// Lanes = 64 i-rows; jj is wave-uniform -> vin via scalar loads; ac coalesced global; ar via LDS transpose.
__global__ __launch_bounds__(256, 4) void k_pass(const float* __restrict__ adj,
                                                 const float* __restrict__ dinv,
                                                 const float* __restrict__ vin,
                                                 float* __restrict__ outp,
                                                 int jchunk) {
  __shared__ float Arow[64*65];      // pad 65: transposed b32 reads are 2-way (free)
  __shared__ float red[4][64][9];
  int b = blockIdx.y, i0 = blockIdx.x*64;
  int t = threadIdx.x, lane = t & 63;
  int wu = __builtin_amdgcn_readfirstlane(t >> 6);   // force SGPR -> scalar loads for vin
  int j0base = blockIdx.z * jchunk;
  const float QV[NIDX] = {0.5f, 1.f/3.f, 0.25f, 0.2f};
  float accr[NIDX], acci[NIDX];
  #pragma unroll
  for (int x = 0; x < NIDX; ++x) { accr[x] = 0.f; acci[x] = 0.f; }

  int njt = jchunk >> 6;
  for (int jt = 0; jt < njt; ++jt) {
    int j0 = j0base + jt*64;
    __syncthreads();
    #pragma unroll
    for (int m = 0; m < 4; ++m) {
      int e4 = t + 256*m;                       // 1024 float4 = 64x64 tile
      int si = e4 >> 4, sj = (e4 & 15) << 2;
      float4 v = *reinterpret_cast<const float4*>(adj + ((size_t)b*NN + i0 + si)*NN + j0 + sj);
      float* dst = &Arow[si*65 + sj];
      dst[0] = v.x; dst[1] = v.y; dst[2] = v.z; dst[3] = v.w;
    }
    __syncthreads();
    const float* acbase = adj + ((size_t)b*NN + j0 + wu*16)*NN + i0 + lane;  // coalesced, row j
    const float* vbase  = vin + ((size_t)(b*NN) + j0 + wu*16)*8;             // uniform -> s_load
    const float* abase  = &Arow[lane*65 + wu*16];
    #pragma unroll 4
    for (int k = 0; k < 16; ++k) {
      float ac = acbase[(size_t)k*NN];          // a[j][i]
      float ar = abase[k];                      // a[i][j]
      float dd = ar - ac;
      float sm = ar + ac;
      float4 v01 = *reinterpret_cast<const float4*>(vbase + k*8);
      float4 v23 = *reinterpret_cast<const float4*>(vbase + k*8 + 4);
      float vr[NIDX] = {v01.x, v01.z, v23.x, v23.z};
      float vi[NIDX] = {v01.y, v01.w, v23.y, v23.w};
      #pragma unroll
      for (int x = 0; x < NIDX; ++x) {
        float u = QV[x]*dd;                     // revolutions, |u| < 0.5
        float sn = FSIN(u), cs = FCOS(u);
        float Mr = sm*cs, Mi = sm*sn;
        accr[x] += Mr*vr[x] - Mi*vi[x];
        acci[x] += Mr*vi[x] + Mi*vr[x];
      }
    }
  }
  #pragma unroll
  for (int x = 0; x < NIDX; ++x) {
    red[wu][lane][x*2]   = accr[x];
    red[wu][lane][x*2+1] = acci[x];
  }
  __syncthreads();
  for (int e = t; e < 64*8; e += 256) {
    int ii = e >> 3, s = e & 7;
    float sum = red[0][ii][s] + red[1][ii][s] + red[2][ii][s] + red[3][ii][s];
    sum *= 0.5f * dinv[b*NN + i0 + ii];
    outp[(size_t)blockIdx.z*(NB*NN*8) + ((size_t)(b*NN) + i0 + ii)*8 + s] = sum;
  }
}

// wtot = dinv_j * (p + sum_c wpart[c])
__global__ void k_comb(const float* __restrict__ dinv, const float* __restrict__ p,
                       const float* __restrict__ wp, float* __restrict__ wt, int JC) {
  int o4 = blockIdx.x*256 + threadIdx.x;        // 16384 float4
  float4 a = reinterpret_cast<const float4*>(p)[o4];
  for (int c = 0; c < JC; ++c) {
    float4 v = reinterpret_cast<const float4*>(wp)[(size_t)c*16384 + o4];
    a.x += v.x; a.y += v.y; a.z += v.z; a.w += v.w;
  }
  float dj = dinv[o4 >> 1];
  a.x *= dj; a.y *= dj; a.z *= dj; a.w *= dj;
  reinterpret_cast<float4*>(wt)[o4] = a;
}

__global__ void k_finish(const float* __restrict__ svec, const float* __restrict__ yp,
                         const float* __restrict__ bias, float* __restrict__ out, int JC) {
  int wI = blockIdx.x*256 + threadIdx.x;        // 0..32767
  int idx = wI & 3, gid = wI >> 2;
  size_t o = (size_t)gid*8 + idx*2;
  float re = svec[o], im = svec[o+1];
  for (int c = 0; c < JC; ++c) {
    re += yp[(size_t)c*65536 + o];
    im += yp[(size_t)c*65536 + o + 1];
  }
  out[wI] = re + bias[idx];
  out[32768 + wI] = im;
}

extern "C" void kernel_launch(void* const* d_in, const int* in_sizes, int n_in,
                              void* d_out, int out_size, void* d_ws, size_t ws_size,
                              hipStream_t stream) {
  (void)in_sizes; (void)n_in; (void)out_size;
  const float* Xr     = (const float*)d_in[0];
  const float* Xi     = (const float*)d_in[1];
  const float* adj    = (const float*)d_in[2];
  const float* weight = (const float*)d_in[3];
  const float* bias   = (const float*)d_in[4];
  float* ws = (float*)d_ws;
  float* rowsum  = ws + OFF_ROW;
  float* colpart = ws + OFF_COLP;
  float* svec    = ws + OFF_S;
  float* pvec    = ws + OFF_P;
  float* rvec    = ws + OFF_R;
  float* dinv    = ws + OFF_DINV;
  float* wtot    = ws + OFF_WT;
  float* wpart   = ws + OFF_WP;   // ypart aliases (wpart dead after k_comb)
  float* out = (float*)d_out;

  int JC = 2;
  if (ws_size >= (size_t)(OFF_WP + 8u*65536u)*4u)      JC = 8;
  else if (ws_size >= (size_t)(OFF_WP + 4u*65536u)*4u) JC = 4;

  k_sums<<<dim3(NB, 64), 512, 0, stream>>>(adj, rowsum, colpart);
  k_dinv<<<dim3(NB*NN/256), 256, 0, stream>>>(rowsum, colpart, dinv);
  k_prep<<<dim3(NB*NN/256), 256, 0, stream>>>(Xr, Xi, weight, dinv, svec, pvec, rvec);
  k_pass<<<dim3(NN/64, NB, JC), 256, 0, stream>>>(adj, dinv, rvec, wpart, NN/JC);
  k_comb<<<dim3(64), 256, 0, stream>>>(dinv, pvec, wpart, wtot, JC);
  k_pass<<<dim3(NN/64, NB, JC), 256, 0, stream>>>(adj, dinv, wtot, wpart, NN/JC);
  k_finish<<<dim3(NB*NN*NIDX/256), 256, 0, stream>>>(svec, wpart, bias, out, JC);
}

// Round 4
// 56.176 us; speedup vs baseline: 1.8153x; 1.1669x over previous
//
#include <hip/hip_runtime.h>
#include <cstddef>

#define NB 8
#define NN 1024
#define NF 32
#define NIDX 4
#define JC 4            // j-chunks per pass (grid z)
#define JCH 256         // j's per chunk
#define NJT 4           // 64-wide j-tiles per chunk

// ---- ws layout (float offsets) ----
#define OFF_ROW   0u
#define OFF_COLP  8192u          // [64][8192]
#define OFF_DINV  532480u
#define OFF_S     540672u        // [8192][8]
#define OFF_P     606208u
#define OFF_R     671744u
#define OFF_WP    737280u        // [JC][65536]

#if __has_builtin(__builtin_amdgcn_sinf)
#define FSIN(x) __builtin_amdgcn_sinf(x)   // sin(2*pi*x), |x|<0.5 here
#define FCOS(x) __builtin_amdgcn_cosf(x)
#else
#define FSIN(x) __sinf((x) * 6.283185307179586f)
#define FCOS(x) __cosf((x) * 6.283185307179586f)
#endif

// Fused row+col sums of adj (one read) + zero d_out for pass2's atomics.
__global__ __launch_bounds__(512) void k_sums(const float* __restrict__ adj,
                                              float* __restrict__ rowsum,
                                              float* __restrict__ colpart,
                                              float* __restrict__ out) {
  int b = blockIdx.x, strip = blockIdx.y;
  int t = threadIdx.x, lane = t & 63, w = t >> 6;
  { int zid = blockIdx.x*64 + blockIdx.y;            // 512 blocks x 128 = 65536
    if (t < 128) out[zid*128 + t] = 0.f; }
  float colreg[16];
  #pragma unroll
  for (int i = 0; i < 16; ++i) colreg[i] = 0.f;
  int r0 = strip*16 + w*2;
  #pragma unroll
  for (int rr = 0; rr < 2; ++rr) {
    const float4* row4 = reinterpret_cast<const float4*>(adj + ((size_t)b*NN + r0 + rr)*NN);
    float rs = 0.f;
    #pragma unroll
    for (int cq = 0; cq < 4; ++cq) {
      float4 v = row4[cq*64 + lane];
      colreg[cq*4+0] += v.x; colreg[cq*4+1] += v.y;
      colreg[cq*4+2] += v.z; colreg[cq*4+3] += v.w;
      rs += (v.x + v.y) + (v.z + v.w);
    }
    #pragma unroll
    for (int o = 32; o > 0; o >>= 1) rs += __shfl_xor(rs, o);
    if (lane == 0) rowsum[b*NN + r0 + rr] = rs;
  }
  __shared__ float cacc[8][NN];
  #pragma unroll
  for (int cq = 0; cq < 4; ++cq)
    #pragma unroll
    for (int x = 0; x < 4; ++x) cacc[w][cq*256 + lane*4 + x] = colreg[cq*4+x];
  __syncthreads();
  for (int c = t; c < NN; c += 512) {
    float s = 0.f;
    #pragma unroll
    for (int ww = 0; ww < 8; ++ww) s += cacc[ww][c];
    colpart[(size_t)strip*(NB*NN) + b*NN + c] = s;
  }
}

// dinv + the three per-node feature contractions (fused).
// s=(w0+w2).X, p=(w1+2w2).X, r=dinv*(-2w2).X
__global__ __launch_bounds__(256) void k_prep(const float* __restrict__ Xr, const float* __restrict__ Xi,
                       const float* __restrict__ weight,
                       const float* __restrict__ rowsum, const float* __restrict__ colpart,
                       float* __restrict__ dinv,
                       float* __restrict__ svec, float* __restrict__ pvec, float* __restrict__ rvec) {
  __shared__ float wsm[NIDX*3*NF];
  int t = threadIdx.x;
  for (int e = t; e < NIDX*3*NF; e += 256) wsm[e] = weight[e];
  __syncthreads();
  int gid = blockIdx.x*256 + t;
  float cs = 0.f;
  for (int k = 0; k < 64; ++k) cs += colpart[(size_t)k*(NB*NN) + gid];
  float D = 0.5f*(rowsum[gid] + cs);
  float di = (D > 0.f) ? (1.0f / sqrtf(D)) : 0.f;
  dinv[gid] = di;
  const float* xr = Xr + (size_t)gid*NF;
  const float* xi = Xi + (size_t)gid*NF;
  float acc[NIDX][3][2];
  #pragma unroll
  for (int x = 0; x < NIDX; ++x)
    #pragma unroll
    for (int v = 0; v < 3; ++v) { acc[x][v][0] = 0.f; acc[x][v][1] = 0.f; }
  for (int f = 0; f < NF; ++f) {
    float xrf = xr[f], xif = xi[f];
    #pragma unroll
    for (int x = 0; x < NIDX; ++x) {
      float w0 = wsm[x*96 + f], w1 = wsm[x*96 + 32 + f], w2 = wsm[x*96 + 64 + f];
      float av = w0 + w2, bv = w1 + 2.f*w2, cv = -2.f*w2;
      acc[x][0][0] += av*xrf; acc[x][0][1] += av*xif;
      acc[x][1][0] += bv*xrf; acc[x][1][1] += bv*xif;
      acc[x][2][0] += cv*xrf; acc[x][2][1] += cv*xif;
    }
  }
  #pragma unroll
  for (int x = 0; x < NIDX; ++x) {
    size_t o = (size_t)gid*8 + x*2;
    svec[o] = acc[x][0][0];      svec[o+1] = acc[x][0][1];
    pvec[o] = acc[x][1][0];      pvec[o+1] = acc[x][1][1];
    rvec[o] = di*acc[x][2][0];   rvec[o+1] = di*acc[x][2][1];
  }
}

// M-application, lanes on j (v reused across 64 i-steps), i wave-uniform.
// MODE 0: vin=rvec (dinv_j prefolded) -> write wpart partials.
// MODE 1: build wtot=dinv*(p+sum wpart) slice in LDS, apply M, atomicAdd into out (+svec+bias on zc==0).
template<int MODE>
__global__ __launch_bounds__(512, 4) void k_pass(const float* __restrict__ adj,
                                                 const float* __restrict__ dinv,
                                                 const float* __restrict__ vin,
                                                 float* __restrict__ wpart,
                                                 const float* __restrict__ svec,
                                                 const float* __restrict__ bias,
                                                 float* __restrict__ out) {
  __shared__ float Tjs[64][65];      // transpose tile, pad-65 -> 2-way (free)
  __shared__ float vlds[JCH][8];     // pass2 wtot slice
  __shared__ float red[8][8*72];     // per-wave [i(8)][slot(8) pad9 x grp(8)]
  int b = blockIdx.y, i0 = blockIdx.x*64, zc = blockIdx.z;
  int j0base = zc*JCH;
  int t = threadIdx.x, lane = t & 63;
  int w = t >> 6;
  int wu = __builtin_amdgcn_readfirstlane(w);
  const float QV[NIDX] = {0.5f, 1.f/3.f, 0.25f, 0.2f};

  if constexpr (MODE == 1) {
    for (int e = t; e < JCH*8; e += 512) {
      int jj = e >> 3, s = e & 7;
      size_t o = ((size_t)b*NN + j0base + jj)*8 + s;
      float v = vin[o];
      #pragma unroll
      for (int c = 0; c < JC; ++c) v += wpart[(size_t)c*65536 + o];
      vlds[jj][s] = v * dinv[b*NN + j0base + jj];
    }
  }

  float accr[8][NIDX], acci[8][NIDX];
  #pragma unroll
  for (int s = 0; s < 8; ++s)
    #pragma unroll
    for (int x = 0; x < NIDX; ++x) { accr[s][x] = 0.f; acci[s][x] = 0.f; }

  for (int jt = 0; jt < NJT; ++jt) {
    int j0 = j0base + jt*64;
    __syncthreads();                               // prev Tjs reads done / vlds ready
    #pragma unroll
    for (int m = 0; m < 2; ++m) {
      int e4 = t + 512*m;                          // 1024 float4 = 64x64 tile
      int jj = e4 >> 4, i4 = (e4 & 15) << 2;
      float4 vv = *reinterpret_cast<const float4*>(adj + ((size_t)b*NN + j0 + jj)*NN + i0 + i4);
      float* dst = &Tjs[jj][i4];
      dst[0] = vv.x; dst[1] = vv.y; dst[2] = vv.z; dst[3] = vv.w;
    }
    float vr[NIDX], vi[NIDX];
    if constexpr (MODE == 0) {
      const float4* vb = reinterpret_cast<const float4*>(vin + ((size_t)b*NN + j0 + lane)*8);
      float4 a = vb[0], c = vb[1];
      vr[0]=a.x; vi[0]=a.y; vr[1]=a.z; vi[1]=a.w;
      vr[2]=c.x; vi[2]=c.y; vr[3]=c.z; vi[3]=c.w;
    } else {
      const float4* vb = reinterpret_cast<const float4*>(&vlds[jt*64 + lane][0]);
      float4 a = vb[0], c = vb[1];
      vr[0]=a.x; vi[0]=a.y; vr[1]=a.z; vi[1]=a.w;
      vr[2]=c.x; vi[2]=c.y; vr[3]=c.z; vi[3]=c.w;
    }
    __syncthreads();                               // tile visible
    const float* arbase = adj + ((size_t)b*NN + i0 + wu*8)*NN + j0 + lane;
    #pragma unroll
    for (int s = 0; s < 8; ++s) {
      float ar = arbase[(size_t)s*NN];             // a[i][j], coalesced
      float ac = Tjs[lane][wu*8 + s];              // a[j][i], 2-way free
      float dd = ar - ac, sm = ar + ac;
      #pragma unroll
      for (int x = 0; x < NIDX; ++x) {
        float u = QV[x]*dd;                        // revolutions, |u|<0.5
        float sn = FSIN(u), cw = FCOS(u);
        float tr = cw*vr[x] - sn*vi[x];
        float ti = cw*vi[x] + sn*vr[x];
        accr[s][x] += sm*tr;
        acci[s][x] += sm*ti;
      }
    }
  }

  // 8x8 in-wave transpose-reduce: lane ends with slot (lane&7) of i-step s,
  // summed over its 8-lane group; static indices only.
  bool b1 = (lane & 1), b2 = (lane & 2), b4 = (lane & 4);
  #pragma unroll
  for (int s = 0; s < 8; ++s) {
    float v0 = accr[s][0], v1 = acci[s][0], v2 = accr[s][1], v3 = acci[s][1];
    float v4 = accr[s][2], v5 = acci[s][2], v6 = accr[s][3], v7 = acci[s][3];
    float k0 = b1 ? v1 : v0, s0 = b1 ? v0 : v1;
    float k1 = b1 ? v3 : v2, s1 = b1 ? v2 : v3;
    float k2 = b1 ? v5 : v4, s2 = b1 ? v4 : v5;
    float k3 = b1 ? v7 : v6, s3 = b1 ? v6 : v7;
    v0 = k0 + __shfl_xor(s0, 1);
    v1 = k1 + __shfl_xor(s1, 1);
    v2 = k2 + __shfl_xor(s2, 1);
    v3 = k3 + __shfl_xor(s3, 1);
    k0 = b2 ? v1 : v0; s0 = b2 ? v0 : v1;
    k1 = b2 ? v3 : v2; s1 = b2 ? v2 : v3;
    v0 = k0 + __shfl_xor(s0, 2);
    v1 = k1 + __shfl_xor(s1, 2);
    k0 = b4 ? v1 : v0; s0 = b4 ? v0 : v1;
    v0 = k0 + __shfl_xor(s0, 4);
    red[w][s*72 + (lane & 7)*9 + (lane >> 3)] = v0;
  }
  __syncthreads();
  {
    int iloc = w*8 + (lane >> 3), slot = lane & 7;
    float sum = 0.f;
    #pragma unroll
    for (int g = 0; g < 8; ++g) sum += red[w][(lane >> 3)*72 + slot*9 + g];
    int i = i0 + iloc;
    float val = sum * 0.5f * dinv[b*NN + i];
    if constexpr (MODE == 0) {
      wpart[(size_t)zc*65536 + ((size_t)b*NN + i)*8 + slot] = val;
    } else {
      if (zc == 0) {
        val += svec[((size_t)b*NN + i)*8 + slot];
        if ((slot & 1) == 0) val += bias[slot >> 1];
      }
      atomicAdd(&out[(slot & 1)*32768 + b*4096 + i*4 + (slot >> 1)], val);
    }
  }
}

extern "C" void kernel_launch(void* const* d_in, const int* in_sizes, int n_in,
                              void* d_out, int out_size, void* d_ws, size_t ws_size,
                              hipStream_t stream) {
  (void)in_sizes; (void)n_in; (void)out_size; (void)ws_size;
  const float* Xr     = (const float*)d_in[0];
  const float* Xi     = (const float*)d_in[1];
  const float* adj    = (const float*)d_in[2];
  const float* weight = (const float*)d_in[3];
  const float* bias   = (const float*)d_in[4];
  float* ws = (float*)d_ws;
  float* rowsum  = ws + OFF_ROW;
  float* colpart = ws + OFF_COLP;
  float* dinv    = ws + OFF_DINV;
  float* svec    = ws + OFF_S;
  float* pvec    = ws + OFF_P;
  float* rvec    = ws + OFF_R;
  float* wpart   = ws + OFF_WP;
  float* out = (float*)d_out;

  k_sums<<<dim3(NB, 64), 512, 0, stream>>>(adj, rowsum, colpart, out);
  k_prep<<<dim3(NB*NN/256), 256, 0, stream>>>(Xr, Xi, weight, rowsum, colpart, dinv, svec, pvec, rvec);
  k_pass<0><<<dim3(NN/64, NB, JC), 512, 0, stream>>>(adj, dinv, rvec, wpart, svec, bias, out);
  k_pass<1><<<dim3(NN/64, NB, JC), 512, 0, stream>>>(adj, dinv, pvec, wpart, svec, bias, out);
}